// Round 1
// baseline (12884.566 us; speedup 1.0000x reference)
//
#include <hip/hip_runtime.h>

#define Gn 4
#define Nn 50000
#define En 800000
#define Bq 32
#define F_IN 64
#define Hn 128
#define HEADS 8
#define HD 16
#define NNODES 50000

// ---------------- degree: deg[c] += 1 over edges ----------------
__global__ __launch_bounds__(256) void k_deg(const int* __restrict__ col, float* __restrict__ deg) {
    int e = blockIdx.x * 256 + threadIdx.x;
    if (e < En) atomicAdd(&deg[col[e]], 1.0f);
}

// ---------------- norm[e] = rsqrt(deg[row]+1)*rsqrt(deg[col]+1) ----------------
__global__ __launch_bounds__(256) void k_norm(const int* __restrict__ row, const int* __restrict__ col,
                                              const float* __restrict__ deg, float* __restrict__ nrm) {
    int e = blockIdx.x * 256 + threadIdx.x;
    if (e < En) nrm[e] = rsqrtf(deg[row[e]] + 1.0f) * rsqrtf(deg[col[e]] + 1.0f);
}

// ---------------- tiled fp32 matmul: out[N,128] = xin[N,K] @ W[K,128] ----------------
template <int K>
__global__ __launch_bounds__(256) void k_mm(const float* __restrict__ xin, const float* __restrict__ W,
                                            float* __restrict__ out, int nrows) {
    __shared__ float Ws[64 * 128];   // 32 KB: one 64-row K-tile of W
    __shared__ float xsT[64 * 36];   // 9 KB: transposed x tile, stride 36 (16B-aligned, conflict-light)
    int t = threadIdx.x;
    int tx = t & 31, ty = t >> 5;    // 32 col-groups x 8 row-groups
    int base = blockIdx.x * 32;
    float acc[4][4];
#pragma unroll
    for (int i = 0; i < 4; ++i)
#pragma unroll
        for (int j = 0; j < 4; ++j) acc[i][j] = 0.f;

    for (int kt = 0; kt < K; kt += 64) {
        const float4* W4 = (const float4*)(W + kt * 128);
        float4* Ws4 = (float4*)Ws;
#pragma unroll
        for (int i = 0; i < 8; ++i) Ws4[t + i * 256] = W4[t + i * 256];
        {
            int r = t >> 4, j4 = (t & 15) << 2;
            float4 v = make_float4(0.f, 0.f, 0.f, 0.f);
            // 32 rows per block but 256 threads cover 16 rows per pass -> 2 passes
#pragma unroll
            for (int p = 0; p < 2; ++p) {
                int rr = r + p * 16;
                if (base + rr < nrows) v = *(const float4*)&xin[(long)(base + rr) * K + kt + j4];
                else v = make_float4(0.f, 0.f, 0.f, 0.f);
                xsT[(j4 + 0) * 36 + rr] = v.x;
                xsT[(j4 + 1) * 36 + rr] = v.y;
                xsT[(j4 + 2) * 36 + rr] = v.z;
                xsT[(j4 + 3) * 36 + rr] = v.w;
            }
        }
        __syncthreads();
#pragma unroll
        for (int jj = 0; jj < 64; ++jj) {
            float4 wv = *(const float4*)&Ws[jj * 128 + tx * 4];
            float4 xv = *(const float4*)&xsT[jj * 36 + ty * 4];
            acc[0][0] += xv.x * wv.x; acc[0][1] += xv.x * wv.y; acc[0][2] += xv.x * wv.z; acc[0][3] += xv.x * wv.w;
            acc[1][0] += xv.y * wv.x; acc[1][1] += xv.y * wv.y; acc[1][2] += xv.y * wv.z; acc[1][3] += xv.y * wv.w;
            acc[2][0] += xv.z * wv.x; acc[2][1] += xv.z * wv.y; acc[2][2] += xv.z * wv.z; acc[2][3] += xv.z * wv.w;
            acc[3][0] += xv.w * wv.x; acc[3][1] += xv.w * wv.y; acc[3][2] += xv.w * wv.z; acc[3][3] += xv.w * wv.w;
        }
        __syncthreads();
    }
#pragma unroll
    for (int i = 0; i < 4; ++i) {
        int r = base + ty * 4 + i;
        if (r < nrows) {
            float4 o = make_float4(acc[i][0], acc[i][1], acc[i][2], acc[i][3]);
            *(float4*)&out[(long)r * 128 + tx * 4] = o;
        }
    }
}

// ---------------- edge scatter: dst[col] += src[row]*norm, 32 threads/edge x float4 ----------------
__global__ __launch_bounds__(256) void k_scatter(const float* __restrict__ src, const int* __restrict__ row,
                                                 const int* __restrict__ col, const float* __restrict__ nrm,
                                                 float* __restrict__ dst) {
    int idx = blockIdx.x * 256 + threadIdx.x;
    int e = idx >> 5;
    if (e >= En) return;
    int f4 = (idx & 31) << 2;
    int r = row[e], c = col[e];
    float nm = nrm[e];
    float4 v = *(const float4*)&src[(long)r * 128 + f4];
    float* d = &dst[(long)c * 128 + f4];
    atomicAdd(d + 0, v.x * nm);
    atomicAdd(d + 1, v.y * nm);
    atomicAdd(d + 2, v.z * nm);
    atomicAdd(d + 3, v.w * nm);
}

// ---------------- self-loop + bias + relu (in place on dst) ----------------
__global__ __launch_bounds__(256) void k_slrelu(float* __restrict__ dst, const float* __restrict__ t,
                                                const float* __restrict__ deg, const float* __restrict__ bias) {
    int idx = blockIdx.x * 256 + threadIdx.x;  // N*32 threads (float4 each)
    if (idx >= Nn * 32) return;
    int n = idx >> 5;
    int f4 = (idx & 31) << 2;
    float inv = 1.0f / (deg[n] + 1.0f);
    float4 a = *(float4*)&dst[(long)n * 128 + f4];
    float4 tv = *(const float4*)&t[(long)n * 128 + f4];
    float4 b = *(const float4*)&bias[f4];
    float4 o;
    o.x = fmaxf(a.x + tv.x * inv + b.x, 0.f);
    o.y = fmaxf(a.y + tv.y * inv + b.y, 0.f);
    o.z = fmaxf(a.z + tv.z * inv + b.z, 0.f);
    o.w = fmaxf(a.w + tv.w * inv + b.w, 0.f);
    *(float4*)&dst[(long)n * 128 + f4] = o;
}

// ---------------- segment mean pool (batch sorted): accumulate sums + counts ----------------
__global__ __launch_bounds__(128) void k_pool(const float* __restrict__ y, const int* __restrict__ batch,
                                              float* __restrict__ emb_sum, float* __restrict__ cnt, int g) {
    int f = threadIdx.x;  // 128
    int start = blockIdx.x * 256;
    int end = min(start + 256, Nn);
    if (start >= Nn) return;
    float acc = 0.f;
    int cacc = 0;
    int cur = batch[start];
    for (int i = start; i < end; ++i) {
        int b = batch[i];
        if (b != cur) {
            atomicAdd(&emb_sum[(g * Bq + cur) * Hn + f], acc);
            if (f == 0) atomicAdd(&cnt[g * Bq + cur], (float)cacc);
            acc = 0.f; cacc = 0; cur = b;
        }
        acc += y[(long)i * Hn + f];
        cacc++;
    }
    atomicAdd(&emb_sum[(g * Bq + cur) * Hn + f], acc);
    if (f == 0) atomicAdd(&cnt[g * Bq + cur], (float)cacc);
}

// ---------------- whole MHA: one block per batch element b ----------------
__global__ __launch_bounds__(128) void k_attn(const float* __restrict__ emb_sum, const float* __restrict__ cnt,
                                              const float* __restrict__ ipw, const float* __restrict__ ipb,
                                              const float* __restrict__ opw, const float* __restrict__ opb,
                                              float* __restrict__ pooled) {
    int b = blockIdx.x;
    int f = threadIdx.x;  // 128
    __shared__ float es[4][128], qs[4][128], ks[4][128], vs[4][128], sc[128], cx[4][128];
#pragma unroll
    for (int g = 0; g < 4; ++g) {
        float c = cnt[g * Bq + b];
        es[g][f] = (c > 0.f) ? emb_sum[(g * Bq + b) * Hn + f] / c : 0.f;
    }
    __syncthreads();
#pragma unroll
    for (int g = 0; g < 4; ++g) {
        float q = ipb[f], k = ipb[Hn + f], v = ipb[2 * Hn + f];
        for (int j = 0; j < Hn; ++j) {
            float e = es[g][j];
            q += e * ipw[f * Hn + j];
            k += e * ipw[(Hn + f) * Hn + j];
            v += e * ipw[(2 * Hn + f) * Hn + j];
        }
        qs[g][f] = q; ks[g][f] = k; vs[g][f] = v;
    }
    __syncthreads();
    {   // scores: t encodes (h,g,kk); scale 1/sqrt(16)=0.25
        int h = f >> 4, g = (f >> 2) & 3, kk = f & 3;
        float s = 0.f;
        for (int d = 0; d < 16; ++d) s += qs[g][h * 16 + d] * ks[kk][h * 16 + d];
        sc[f] = s * 0.25f;
    }
    __syncthreads();
    {   // softmax over kk + ctx
        int h = f >> 4;
#pragma unroll
        for (int g = 0; g < 4; ++g) {
            int bi = h * 16 + g * 4;
            float s0 = sc[bi], s1 = sc[bi + 1], s2 = sc[bi + 2], s3 = sc[bi + 3];
            float m = fmaxf(fmaxf(s0, s1), fmaxf(s2, s3));
            float e0 = __expf(s0 - m), e1 = __expf(s1 - m), e2 = __expf(s2 - m), e3 = __expf(s3 - m);
            float rinv = 1.f / (e0 + e1 + e2 + e3);
            cx[g][f] = (e0 * vs[0][f] + e1 * vs[1][f] + e2 * vs[2][f] + e3 * vs[3][f]) * rinv;
        }
    }
    __syncthreads();
#pragma unroll
    for (int g = 0; g < 4; ++g) {
        float a = opb[f];
        for (int j = 0; j < Hn; ++j) a += cx[g][j] * opw[f * Hn + j];
        atomicAdd(&pooled[g * Hn + f], a * (1.0f / Bq));
    }
}

// ---------------- final: out[g,n] = (pooled[g] . lin_w[n]) + lin_b[n], *60+50 ----------------
__global__ __launch_bounds__(256) void k_final(const float* __restrict__ pooled, const float* __restrict__ lw,
                                               const float* __restrict__ lb, float* __restrict__ out) {
    __shared__ float ps[512];
    int t = threadIdx.x;
    ps[t] = pooled[t];
    ps[t + 256] = pooled[t + 256];
    __syncthreads();
    int wave = t >> 6, lane = t & 63;
    int n = blockIdx.x * 4 + wave;
    if (n >= NNODES) return;
    float2 w = *(const float2*)&lw[(long)n * 128 + lane * 2];
    float a0 = w.x * ps[0 * 128 + lane * 2] + w.y * ps[0 * 128 + lane * 2 + 1];
    float a1 = w.x * ps[1 * 128 + lane * 2] + w.y * ps[1 * 128 + lane * 2 + 1];
    float a2 = w.x * ps[2 * 128 + lane * 2] + w.y * ps[2 * 128 + lane * 2 + 1];
    float a3 = w.x * ps[3 * 128 + lane * 2] + w.y * ps[3 * 128 + lane * 2 + 1];
#pragma unroll
    for (int off = 32; off > 0; off >>= 1) {
        a0 += __shfl_down(a0, off);
        a1 += __shfl_down(a1, off);
        a2 += __shfl_down(a2, off);
        a3 += __shfl_down(a3, off);
    }
    if (lane == 0) {
        float bn = lb[n];
        out[0 * NNODES + n] = (a0 + bn) * 60.f + 50.f;
        out[1 * NNODES + n] = (a1 + bn) * 60.f + 50.f;
        out[2 * NNODES + n] = (a2 + bn) * 60.f + 50.f;
        out[3 * NNODES + n] = (a3 + bn) * 60.f + 50.f;
    }
}

extern "C" void kernel_launch(void* const* d_in, const int* in_sizes, int n_in,
                              void* d_out, int out_size, void* d_ws, size_t ws_size,
                              hipStream_t stream) {
    const float* x   = (const float*)d_in[0];   // [G,N,64]
    const int*   ei  = (const int*)d_in[1];     // [G,2,E]
    const int*   bat = (const int*)d_in[2];     // [G,N]
    const float* W1  = (const float*)d_in[3];
    const float* b1  = (const float*)d_in[4];
    const float* W2  = (const float*)d_in[5];
    const float* b2  = (const float*)d_in[6];
    const float* ipw = (const float*)d_in[7];
    const float* ipb = (const float*)d_in[8];
    const float* opw = (const float*)d_in[9];
    const float* opb = (const float*)d_in[10];
    const float* lw  = (const float*)d_in[11];
    const float* lb  = (const float*)d_in[12];
    float* out = (float*)d_out;

    // workspace carve-up (floats)
    float* A      = (float*)d_ws;               // [N,128]
    float* Bb     = A + (size_t)Nn * Hn;        // [N,128]
    float* deg    = Bb + (size_t)Nn * Hn;       // [N]
    float* nrm    = deg + 51200;                // [E]
    float* emb    = nrm + En;                   // [G,B,H]
    float* cnt    = emb + Gn * Bq * Hn;         // [G,B]
    float* pooled = cnt + Gn * Bq;              // [G,H]

    hipMemsetAsync(emb, 0, Gn * Bq * Hn * sizeof(float), stream);
    hipMemsetAsync(cnt, 0, Gn * Bq * sizeof(float), stream);
    hipMemsetAsync(pooled, 0, Gn * Hn * sizeof(float), stream);

    const int mmGrid = (Nn + 31) / 32;           // 1563
    const int egGrid = (En + 255) / 256;         // 3125
    const int scGrid = (En * 32) / 256;          // 100000
    const int slGrid = (Nn * 32) / 256;          // 6250
    const int plGrid = (Nn + 255) / 256;         // 196

    for (int g = 0; g < Gn; ++g) {
        const int* row = ei + (size_t)g * 2 * En;
        const int* col = row + En;
        const float* xg = x + (size_t)g * Nn * F_IN;
        const int* bg = bat + (size_t)g * Nn;

        hipMemsetAsync(deg, 0, Nn * sizeof(float), stream);
        k_deg<<<egGrid, 256, 0, stream>>>(col, deg);
        k_norm<<<egGrid, 256, 0, stream>>>(row, col, deg, nrm);

        // layer 1
        k_mm<64><<<mmGrid, 256, 0, stream>>>(xg, W1, A, Nn);
        hipMemsetAsync(Bb, 0, (size_t)Nn * Hn * sizeof(float), stream);
        k_scatter<<<scGrid, 256, 0, stream>>>(A, row, col, nrm, Bb);
        k_slrelu<<<slGrid, 256, 0, stream>>>(Bb, A, deg, b1);

        // layer 2
        k_mm<128><<<mmGrid, 256, 0, stream>>>(Bb, W2, A, Nn);
        hipMemsetAsync(Bb, 0, (size_t)Nn * Hn * sizeof(float), stream);
        k_scatter<<<scGrid, 256, 0, stream>>>(A, row, col, nrm, Bb);
        k_slrelu<<<slGrid, 256, 0, stream>>>(Bb, A, deg, b2);

        // pool
        k_pool<<<plGrid, 128, 0, stream>>>(Bb, bg, emb, cnt, g);
    }

    k_attn<<<Bq, 128, 0, stream>>>(emb, cnt, ipw, ipb, opw, opb, pooled);
    k_final<<<(NNODES + 3) / 4, 256, 0, stream>>>(pooled, lw, lb, out);
}

// Round 2
// 3096.835 us; speedup vs baseline: 4.1606x; 4.1606x over previous
//
#include <hip/hip_runtime.h>

#define Gn 4
#define Nn 50000
#define En 800000
#define Bq 32
#define F_IN 64
#define Hn 128
#define HEADS 8
#define HD 16
#define NNODES 50000

// ---------------- degree: degi[c] += 1 over edges ----------------
__global__ __launch_bounds__(256) void k_deg(const int* __restrict__ col, int* __restrict__ degi) {
    int e = blockIdx.x * 256 + threadIdx.x;
    if (e < En) atomicAdd(&degi[col[e]], 1);
}

// ---------------- single-block exclusive scan of degi -> off[N+1]; zero cursors ----------------
__global__ __launch_bounds__(256) void k_scan(const int* __restrict__ degi, int* __restrict__ off,
                                              int* __restrict__ cur) {
    __shared__ int ssum[256];
    const int CH = (Nn + 255) / 256;  // 196
    int t = threadIdx.x;
    int beg = t * CH, end = min(beg + CH, Nn);
    int s = 0;
    for (int i = beg; i < end; ++i) s += degi[i];
    ssum[t] = s;
    __syncthreads();
    for (int d = 1; d < 256; d <<= 1) {
        int v = (t >= d) ? ssum[t - d] : 0;
        __syncthreads();
        ssum[t] += v;
        __syncthreads();
    }
    int run = (t > 0) ? ssum[t - 1] : 0;
    for (int i = beg; i < end; ++i) { off[i] = run; run += degi[i]; cur[i] = 0; }
    if (t == 255) off[Nn] = ssum[255];
}

// ---------------- fill CSR: srcs/wts sorted by destination ----------------
__global__ __launch_bounds__(256) void k_fill(const int* __restrict__ row, const int* __restrict__ col,
                                              const int* __restrict__ degi, const int* __restrict__ off,
                                              int* __restrict__ cur, int* __restrict__ srcs,
                                              float* __restrict__ wts) {
    int e = blockIdx.x * 256 + threadIdx.x;
    if (e >= En) return;
    int r = row[e], c = col[e];
    float w = rsqrtf((float)degi[r] + 1.0f) * rsqrtf((float)degi[c] + 1.0f);
    int pos = off[c] + atomicAdd(&cur[c], 1);
    srcs[pos] = r;
    wts[pos] = w;
}

// ---------------- tiled fp32 matmul: out[N,128] = xin[N,K] @ W[K,128] ----------------
template <int K>
__global__ __launch_bounds__(256) void k_mm(const float* __restrict__ xin, const float* __restrict__ W,
                                            float* __restrict__ out, int nrows) {
    __shared__ float Ws[64 * 128];
    __shared__ float xsT[64 * 36];
    int t = threadIdx.x;
    int tx = t & 31, ty = t >> 5;
    int base = blockIdx.x * 32;
    float acc[4][4];
#pragma unroll
    for (int i = 0; i < 4; ++i)
#pragma unroll
        for (int j = 0; j < 4; ++j) acc[i][j] = 0.f;

    for (int kt = 0; kt < K; kt += 64) {
        const float4* W4 = (const float4*)(W + kt * 128);
        float4* Ws4 = (float4*)Ws;
#pragma unroll
        for (int i = 0; i < 8; ++i) Ws4[t + i * 256] = W4[t + i * 256];
        {
            int r = t >> 4, j4 = (t & 15) << 2;
            float4 v;
#pragma unroll
            for (int p = 0; p < 2; ++p) {
                int rr = r + p * 16;
                if (base + rr < nrows) v = *(const float4*)&xin[(long)(base + rr) * K + kt + j4];
                else v = make_float4(0.f, 0.f, 0.f, 0.f);
                xsT[(j4 + 0) * 36 + rr] = v.x;
                xsT[(j4 + 1) * 36 + rr] = v.y;
                xsT[(j4 + 2) * 36 + rr] = v.z;
                xsT[(j4 + 3) * 36 + rr] = v.w;
            }
        }
        __syncthreads();
#pragma unroll
        for (int jj = 0; jj < 64; ++jj) {
            float4 wv = *(const float4*)&Ws[jj * 128 + tx * 4];
            float4 xv = *(const float4*)&xsT[jj * 36 + ty * 4];
            acc[0][0] += xv.x * wv.x; acc[0][1] += xv.x * wv.y; acc[0][2] += xv.x * wv.z; acc[0][3] += xv.x * wv.w;
            acc[1][0] += xv.y * wv.x; acc[1][1] += xv.y * wv.y; acc[1][2] += xv.y * wv.z; acc[1][3] += xv.y * wv.w;
            acc[2][0] += xv.z * wv.x; acc[2][1] += xv.z * wv.y; acc[2][2] += xv.z * wv.z; acc[2][3] += xv.z * wv.w;
            acc[3][0] += xv.w * wv.x; acc[3][1] += xv.w * wv.y; acc[3][2] += xv.w * wv.z; acc[3][3] += xv.w * wv.w;
        }
        __syncthreads();
    }
#pragma unroll
    for (int i = 0; i < 4; ++i) {
        int r = base + ty * 4 + i;
        if (r < nrows) {
            float4 o = make_float4(acc[i][0], acc[i][1], acc[i][2], acc[i][3]);
            *(float4*)&out[(long)r * 128 + tx * 4] = o;
        }
    }
}

// ---------------- gather aggregation + self-loop + bias + relu (no atomics) ----------------
// 32 lanes per node (each lane owns a float4 of 128 features), 8 nodes per block.
__global__ __launch_bounds__(256) void k_agg(const float* __restrict__ h, const int* __restrict__ off,
                                             const int* __restrict__ srcs, const float* __restrict__ wts,
                                             const int* __restrict__ degi, const float* __restrict__ bias,
                                             float* __restrict__ out) {
    int node = blockIdx.x * 8 + (threadIdx.x >> 5);
    int lane = threadIdx.x & 31;
    int f4 = lane << 2;
    int beg = off[node], end = off[node + 1];
    float4 acc = make_float4(0.f, 0.f, 0.f, 0.f);
    for (int e = beg; e < end; e += 32) {
        int k = min(32, end - e);
        int sid = 0; float w = 0.f;
        if (lane < k) { sid = srcs[e + lane]; w = wts[e + lane]; }
        for (int j = 0; j < k; ++j) {
            int s = __shfl(sid, j, 32);
            float ww = __shfl(w, j, 32);
            float4 v = *(const float4*)&h[(long)s * 128 + f4];
            acc.x += v.x * ww;
            acc.y += v.y * ww;
            acc.z += v.z * ww;
            acc.w += v.w * ww;
        }
    }
    float inv = 1.0f / ((float)degi[node] + 1.0f);
    float4 tv = *(const float4*)&h[(long)node * 128 + f4];
    float4 b = *(const float4*)&bias[f4];
    float4 o;
    o.x = fmaxf(acc.x + tv.x * inv + b.x, 0.f);
    o.y = fmaxf(acc.y + tv.y * inv + b.y, 0.f);
    o.z = fmaxf(acc.z + tv.z * inv + b.z, 0.f);
    o.w = fmaxf(acc.w + tv.w * inv + b.w, 0.f);
    *(float4*)&out[(long)node * 128 + f4] = o;
}

// ---------------- segment mean pool (batch sorted): accumulate sums + counts ----------------
__global__ __launch_bounds__(128) void k_pool(const float* __restrict__ y, const int* __restrict__ batch,
                                              float* __restrict__ emb_sum, float* __restrict__ cnt, int g) {
    int f = threadIdx.x;  // 128
    int start = blockIdx.x * 256;
    int end = min(start + 256, Nn);
    if (start >= Nn) return;
    float acc = 0.f;
    int cacc = 0;
    int cur = batch[start];
    for (int i = start; i < end; ++i) {
        int b = batch[i];
        if (b != cur) {
            atomicAdd(&emb_sum[(g * Bq + cur) * Hn + f], acc);
            if (f == 0) atomicAdd(&cnt[g * Bq + cur], (float)cacc);
            acc = 0.f; cacc = 0; cur = b;
        }
        acc += y[(long)i * Hn + f];
        cacc++;
    }
    atomicAdd(&emb_sum[(g * Bq + cur) * Hn + f], acc);
    if (f == 0) atomicAdd(&cnt[g * Bq + cur], (float)cacc);
}

// ---------------- whole MHA: one block per batch element b ----------------
__global__ __launch_bounds__(128) void k_attn(const float* __restrict__ emb_sum, const float* __restrict__ cnt,
                                              const float* __restrict__ ipw, const float* __restrict__ ipb,
                                              const float* __restrict__ opw, const float* __restrict__ opb,
                                              float* __restrict__ pooled) {
    int b = blockIdx.x;
    int f = threadIdx.x;  // 128
    __shared__ float es[4][128], qs[4][128], ks[4][128], vs[4][128], sc[128], cx[4][128];
#pragma unroll
    for (int g = 0; g < 4; ++g) {
        float c = cnt[g * Bq + b];
        es[g][f] = (c > 0.f) ? emb_sum[(g * Bq + b) * Hn + f] / c : 0.f;
    }
    __syncthreads();
#pragma unroll
    for (int g = 0; g < 4; ++g) {
        float q = ipb[f], k = ipb[Hn + f], v = ipb[2 * Hn + f];
        for (int j = 0; j < Hn; ++j) {
            float e = es[g][j];
            q += e * ipw[f * Hn + j];
            k += e * ipw[(Hn + f) * Hn + j];
            v += e * ipw[(2 * Hn + f) * Hn + j];
        }
        qs[g][f] = q; ks[g][f] = k; vs[g][f] = v;
    }
    __syncthreads();
    {
        int h = f >> 4, g = (f >> 2) & 3, kk = f & 3;
        float s = 0.f;
        for (int d = 0; d < 16; ++d) s += qs[g][h * 16 + d] * ks[kk][h * 16 + d];
        sc[f] = s * 0.25f;
    }
    __syncthreads();
    {
        int h = f >> 4;
#pragma unroll
        for (int g = 0; g < 4; ++g) {
            int bi = h * 16 + g * 4;
            float s0 = sc[bi], s1 = sc[bi + 1], s2 = sc[bi + 2], s3 = sc[bi + 3];
            float m = fmaxf(fmaxf(s0, s1), fmaxf(s2, s3));
            float e0 = __expf(s0 - m), e1 = __expf(s1 - m), e2 = __expf(s2 - m), e3 = __expf(s3 - m);
            float rinv = 1.f / (e0 + e1 + e2 + e3);
            cx[g][f] = (e0 * vs[0][f] + e1 * vs[1][f] + e2 * vs[2][f] + e3 * vs[3][f]) * rinv;
        }
    }
    __syncthreads();
#pragma unroll
    for (int g = 0; g < 4; ++g) {
        float a = opb[f];
        for (int j = 0; j < Hn; ++j) a += cx[g][j] * opw[f * Hn + j];
        atomicAdd(&pooled[g * Hn + f], a * (1.0f / Bq));
    }
}

// ---------------- final: out[g,n] = (pooled[g] . lin_w[n]) + lin_b[n], *60+50 ----------------
__global__ __launch_bounds__(256) void k_final(const float* __restrict__ pooled, const float* __restrict__ lw,
                                               const float* __restrict__ lb, float* __restrict__ out) {
    __shared__ float ps[512];
    int t = threadIdx.x;
    ps[t] = pooled[t];
    ps[t + 256] = pooled[t + 256];
    __syncthreads();
    int wave = t >> 6, lane = t & 63;
    int n = blockIdx.x * 4 + wave;
    if (n >= NNODES) return;
    float2 w = *(const float2*)&lw[(long)n * 128 + lane * 2];
    float a0 = w.x * ps[0 * 128 + lane * 2] + w.y * ps[0 * 128 + lane * 2 + 1];
    float a1 = w.x * ps[1 * 128 + lane * 2] + w.y * ps[1 * 128 + lane * 2 + 1];
    float a2 = w.x * ps[2 * 128 + lane * 2] + w.y * ps[2 * 128 + lane * 2 + 1];
    float a3 = w.x * ps[3 * 128 + lane * 2] + w.y * ps[3 * 128 + lane * 2 + 1];
#pragma unroll
    for (int off = 32; off > 0; off >>= 1) {
        a0 += __shfl_down(a0, off);
        a1 += __shfl_down(a1, off);
        a2 += __shfl_down(a2, off);
        a3 += __shfl_down(a3, off);
    }
    if (lane == 0) {
        float bn = lb[n];
        out[0 * NNODES + n] = (a0 + bn) * 60.f + 50.f;
        out[1 * NNODES + n] = (a1 + bn) * 60.f + 50.f;
        out[2 * NNODES + n] = (a2 + bn) * 60.f + 50.f;
        out[3 * NNODES + n] = (a3 + bn) * 60.f + 50.f;
    }
}

extern "C" void kernel_launch(void* const* d_in, const int* in_sizes, int n_in,
                              void* d_out, int out_size, void* d_ws, size_t ws_size,
                              hipStream_t stream) {
    const float* x   = (const float*)d_in[0];
    const int*   ei  = (const int*)d_in[1];
    const int*   bat = (const int*)d_in[2];
    const float* W1  = (const float*)d_in[3];
    const float* b1  = (const float*)d_in[4];
    const float* W2  = (const float*)d_in[5];
    const float* b2  = (const float*)d_in[6];
    const float* ipw = (const float*)d_in[7];
    const float* ipb = (const float*)d_in[8];
    const float* opw = (const float*)d_in[9];
    const float* opb = (const float*)d_in[10];
    const float* lw  = (const float*)d_in[11];
    const float* lb  = (const float*)d_in[12];
    float* out = (float*)d_out;

    // workspace carve-up (floats / ints)
    float* A      = (float*)d_ws;               // [N,128] 25.6MB
    float* Bb     = A + (size_t)Nn * Hn;        // [N,128] 25.6MB
    int*   degi   = (int*)(Bb + (size_t)Nn * Hn);  // [N]
    int*   off    = degi + 51200;               // [N+1]
    int*   cur    = off + 51208;                // [N]
    int*   srcs   = cur + 51200;                // [E] 3.2MB
    float* wts    = (float*)(srcs + En);        // [E] 3.2MB
    float* emb    = wts + En;                   // [G,B,H]
    float* cnt    = emb + Gn * Bq * Hn;         // [G,B]
    float* pooled = cnt + Gn * Bq;              // [G,H]

    hipMemsetAsync(emb, 0, Gn * Bq * Hn * sizeof(float), stream);
    hipMemsetAsync(cnt, 0, Gn * Bq * sizeof(float), stream);
    hipMemsetAsync(pooled, 0, Gn * Hn * sizeof(float), stream);

    const int mmGrid = (Nn + 31) / 32;    // 1563
    const int egGrid = (En + 255) / 256;  // 3125
    const int agGrid = (Nn + 7) / 8;      // 6250
    const int plGrid = (Nn + 255) / 256;  // 196

    for (int g = 0; g < Gn; ++g) {
        const int* row = ei + (size_t)g * 2 * En;
        const int* col = row + En;
        const float* xg = x + (size_t)g * Nn * F_IN;
        const int* bg = bat + (size_t)g * Nn;

        // CSR build
        hipMemsetAsync(degi, 0, Nn * sizeof(int), stream);
        k_deg<<<egGrid, 256, 0, stream>>>(col, degi);
        k_scan<<<1, 256, 0, stream>>>(degi, off, cur);
        k_fill<<<egGrid, 256, 0, stream>>>(row, col, degi, off, cur, srcs, wts);

        // layer 1: h = x@W1 ; agg+selfloop+bias+relu
        k_mm<64><<<mmGrid, 256, 0, stream>>>(xg, W1, A, Nn);
        k_agg<<<agGrid, 256, 0, stream>>>(A, off, srcs, wts, degi, b1, Bb);

        // layer 2
        k_mm<128><<<mmGrid, 256, 0, stream>>>(Bb, W2, A, Nn);
        k_agg<<<agGrid, 256, 0, stream>>>(A, off, srcs, wts, degi, b2, Bb);

        // pool
        k_pool<<<plGrid, 128, 0, stream>>>(Bb, bg, emb, cnt, g);
    }

    k_attn<<<Bq, 128, 0, stream>>>(emb, cnt, ipw, ipb, opw, opb, pooled);
    k_final<<<(NNODES + 3) / 4, 256, 0, stream>>>(pooled, lw, lb, out);
}

// Round 3
// 1762.500 us; speedup vs baseline: 7.3104x; 1.7571x over previous
//
#include <hip/hip_runtime.h>

#define Gn 4
#define Nn 50000
#define En 800000
#define Bq 32
#define F_IN 64
#define Hn 128
#define HEADS 8
#define HD 16
#define NNODES 50000

// ---- bf16 helpers (RNE) ----
__device__ __forceinline__ float bf2f(unsigned short u) {
    unsigned int x = ((unsigned int)u) << 16;
    float f; __builtin_memcpy(&f, &x, 4); return f;
}
__device__ __forceinline__ unsigned short f2bf(float f) {
    unsigned int x; __builtin_memcpy(&x, &f, 4);
    x = (x + 0x7fffu + ((x >> 16) & 1u)) >> 16;
    return (unsigned short)x;
}

// ---------------- cast fp32 x -> bf16 xb ----------------
__global__ __launch_bounds__(256) void k_cast(const float* __restrict__ x, unsigned short* __restrict__ xb) {
    int i = blockIdx.x * 256 + threadIdx.x;  // one float4 per thread
    if (i >= Nn * F_IN / 4) return;
    float4 v = *(const float4*)&x[i * 4];
    ushort4 u = make_ushort4(f2bf(v.x), f2bf(v.y), f2bf(v.z), f2bf(v.w));
    *(ushort4*)&xb[i * 4] = u;
}

// ---------------- degree ----------------
__global__ __launch_bounds__(256) void k_deg(const int* __restrict__ col, int* __restrict__ degi) {
    int e = blockIdx.x * 256 + threadIdx.x;
    if (e < En) atomicAdd(&degi[col[e]], 1);
}

// ---------------- single-block exclusive scan -> off[N+1]; zero cursors ----------------
__global__ __launch_bounds__(1024) void k_scan(const int* __restrict__ degi, int* __restrict__ off,
                                               int* __restrict__ cur) {
    __shared__ int ssum[1024];
    const int CH = (Nn + 1023) / 1024;  // 49
    int t = threadIdx.x;
    int beg = t * CH, end = min(beg + CH, Nn);
    int s = 0;
    for (int i = beg; i < end; ++i) s += degi[i];
    ssum[t] = s;
    __syncthreads();
    for (int d = 1; d < 1024; d <<= 1) {
        int v = (t >= d) ? ssum[t - d] : 0;
        __syncthreads();
        ssum[t] += v;
        __syncthreads();
    }
    int run = (t > 0) ? ssum[t - 1] : 0;
    for (int i = beg; i < end; ++i) { off[i] = run; run += degi[i]; cur[i] = 0; }
    if (t == 1023) off[Nn] = ssum[1023];
}

// ---------------- fill CSR (dest-sorted) ----------------
__global__ __launch_bounds__(256) void k_fill(const int* __restrict__ row, const int* __restrict__ col,
                                              const int* __restrict__ degi, const int* __restrict__ off,
                                              int* __restrict__ cur, int* __restrict__ srcs,
                                              float* __restrict__ wts) {
    int e = blockIdx.x * 256 + threadIdx.x;
    if (e >= En) return;
    int r = row[e], c = col[e];
    float w = rsqrtf((float)degi[r] + 1.0f) * rsqrtf((float)degi[c] + 1.0f);
    int pos = off[c] + atomicAdd(&cur[c], 1);
    srcs[pos] = r;
    wts[pos] = w;
}

// ---------------- agg on 64-feat bf16 (layer-1, pre-projection) ----------------
// 8 nodes/block, 32 lanes/node, lane owns 2 features (ushort2 = 4B).
__global__ __launch_bounds__(256) void k_agg1(const unsigned short* __restrict__ xb, const int* __restrict__ off,
                                              const int* __restrict__ srcs, const float* __restrict__ wts,
                                              const int* __restrict__ degi, unsigned short* __restrict__ z1) {
    int node = blockIdx.x * 8 + (threadIdx.x >> 5);
    int lane = threadIdx.x & 31;
    int f2 = lane << 1;
    int beg = off[node], end = off[node + 1];
    float ax = 0.f, ay = 0.f;
    for (int e = beg; e < end; e += 32) {
        int k = min(32, end - e);
        int sid = 0; float w = 0.f;
        if (lane < k) { sid = srcs[e + lane]; w = wts[e + lane]; }
        for (int j = 0; j < k; ++j) {
            int s = __shfl(sid, j, 32);
            float ww = __shfl(w, j, 32);
            ushort2 u = *(const ushort2*)&xb[(long)s * 64 + f2];
            ax += bf2f(u.x) * ww;
            ay += bf2f(u.y) * ww;
        }
    }
    float inv = 1.0f / ((float)degi[node] + 1.0f);
    ushort2 su = *(const ushort2*)&xb[(long)node * 64 + f2];
    ax += bf2f(su.x) * inv;
    ay += bf2f(su.y) * inv;
    *(ushort2*)&z1[(long)node * 64 + f2] = make_ushort2(f2bf(ax), f2bf(ay));
}

// ---------------- agg on 128-feat bf16 (layer-2, pre-projection) ----------------
// 8 nodes/block, 32 lanes/node, lane owns 4 features (ushort4 = 8B).
__global__ __launch_bounds__(256) void k_agg2(const unsigned short* __restrict__ h, const int* __restrict__ off,
                                              const int* __restrict__ srcs, const float* __restrict__ wts,
                                              const int* __restrict__ degi, unsigned short* __restrict__ z2) {
    int node = blockIdx.x * 8 + (threadIdx.x >> 5);
    int lane = threadIdx.x & 31;
    int f4 = lane << 2;
    int beg = off[node], end = off[node + 1];
    float a0 = 0.f, a1 = 0.f, a2 = 0.f, a3 = 0.f;
    for (int e = beg; e < end; e += 32) {
        int k = min(32, end - e);
        int sid = 0; float w = 0.f;
        if (lane < k) { sid = srcs[e + lane]; w = wts[e + lane]; }
        for (int j = 0; j < k; ++j) {
            int s = __shfl(sid, j, 32);
            float ww = __shfl(w, j, 32);
            ushort4 u = *(const ushort4*)&h[(long)s * 128 + f4];
            a0 += bf2f(u.x) * ww;
            a1 += bf2f(u.y) * ww;
            a2 += bf2f(u.z) * ww;
            a3 += bf2f(u.w) * ww;
        }
    }
    float inv = 1.0f / ((float)degi[node] + 1.0f);
    ushort4 su = *(const ushort4*)&h[(long)node * 128 + f4];
    a0 += bf2f(su.x) * inv;
    a1 += bf2f(su.y) * inv;
    a2 += bf2f(su.z) * inv;
    a3 += bf2f(su.w) * inv;
    *(ushort4*)&z2[(long)node * 128 + f4] = make_ushort4(f2bf(a0), f2bf(a1), f2bf(a2), f2bf(a3));
}

// ---------------- mm: out = relu(zin_bf16[N,K] @ W[K,128] + b); OUTBF: bf16 or fp32 out ----------------
template <int K, int OUTBF>
__global__ __launch_bounds__(256, 3) void k_mm(const unsigned short* __restrict__ zin,
                                               const float* __restrict__ W, const float* __restrict__ bias,
                                               void* __restrict__ outp, int nrows) {
    __shared__ float Ws[64 * 128];   // 32 KB per 64-K tile
    __shared__ float xsT[64 * 36];   // 9 KB transposed x tile
    int t = threadIdx.x;
    int tx = t & 31, ty = t >> 5;
    int base = blockIdx.x * 32;
    float acc[4][4];
#pragma unroll
    for (int i = 0; i < 4; ++i)
#pragma unroll
        for (int j = 0; j < 4; ++j) acc[i][j] = 0.f;

    for (int kt = 0; kt < K; kt += 64) {
        const float4* W4 = (const float4*)(W + kt * 128);
        float4* Ws4 = (float4*)Ws;
#pragma unroll
        for (int i = 0; i < 8; ++i) Ws4[t + i * 256] = W4[t + i * 256];
        {
            int r = t >> 4, j4 = (t & 15) << 2;
#pragma unroll
            for (int p = 0; p < 2; ++p) {
                int rr = r + p * 16;
                int grow = base + rr;
                ushort4 u = make_ushort4(0, 0, 0, 0);
                if (grow < nrows) u = *(const ushort4*)&zin[(long)grow * K + kt + j4];
                xsT[(j4 + 0) * 36 + rr] = bf2f(u.x);
                xsT[(j4 + 1) * 36 + rr] = bf2f(u.y);
                xsT[(j4 + 2) * 36 + rr] = bf2f(u.z);
                xsT[(j4 + 3) * 36 + rr] = bf2f(u.w);
            }
        }
        __syncthreads();
#pragma unroll 8
        for (int jj = 0; jj < 64; ++jj) {
            float4 wv = *(const float4*)&Ws[jj * 128 + tx * 4];
            float4 xv = *(const float4*)&xsT[jj * 36 + ty * 4];
            acc[0][0] += xv.x * wv.x; acc[0][1] += xv.x * wv.y; acc[0][2] += xv.x * wv.z; acc[0][3] += xv.x * wv.w;
            acc[1][0] += xv.y * wv.x; acc[1][1] += xv.y * wv.y; acc[1][2] += xv.y * wv.z; acc[1][3] += xv.y * wv.w;
            acc[2][0] += xv.z * wv.x; acc[2][1] += xv.z * wv.y; acc[2][2] += xv.z * wv.z; acc[2][3] += xv.z * wv.w;
            acc[3][0] += xv.w * wv.x; acc[3][1] += xv.w * wv.y; acc[3][2] += xv.w * wv.z; acc[3][3] += xv.w * wv.w;
        }
        __syncthreads();
    }
    float4 bv = *(const float4*)&bias[tx * 4];
#pragma unroll
    for (int i = 0; i < 4; ++i) {
        int r = base + ty * 4 + i;
        if (r < nrows) {
            float o0 = fmaxf(acc[i][0] + bv.x, 0.f);
            float o1 = fmaxf(acc[i][1] + bv.y, 0.f);
            float o2 = fmaxf(acc[i][2] + bv.z, 0.f);
            float o3 = fmaxf(acc[i][3] + bv.w, 0.f);
            if (OUTBF) {
                ushort4 st = make_ushort4(f2bf(o0), f2bf(o1), f2bf(o2), f2bf(o3));
                *(ushort4*)&((unsigned short*)outp)[(long)r * 128 + tx * 4] = st;
            } else {
                *(float4*)&((float*)outp)[(long)r * 128 + tx * 4] = make_float4(o0, o1, o2, o3);
            }
        }
    }
}

// ---------------- segment mean pool (batch sorted) ----------------
__global__ __launch_bounds__(128) void k_pool(const float* __restrict__ y, const int* __restrict__ batch,
                                              float* __restrict__ emb_sum, float* __restrict__ cnt, int g) {
    int f = threadIdx.x;  // 128
    int start = blockIdx.x * 256;
    int end = min(start + 256, Nn);
    if (start >= Nn) return;
    float acc = 0.f;
    int cacc = 0;
    int cur = batch[start];
    for (int i = start; i < end; ++i) {
        int b = batch[i];
        if (b != cur) {
            atomicAdd(&emb_sum[(g * Bq + cur) * Hn + f], acc);
            if (f == 0) atomicAdd(&cnt[g * Bq + cur], (float)cacc);
            acc = 0.f; cacc = 0; cur = b;
        }
        acc += y[(long)i * Hn + f];
        cacc++;
    }
    atomicAdd(&emb_sum[(g * Bq + cur) * Hn + f], acc);
    if (f == 0) atomicAdd(&cnt[g * Bq + cur], (float)cacc);
}

// ---------------- whole MHA: one block per batch element b ----------------
__global__ __launch_bounds__(128) void k_attn(const float* __restrict__ emb_sum, const float* __restrict__ cnt,
                                              const float* __restrict__ ipw, const float* __restrict__ ipb,
                                              const float* __restrict__ opw, const float* __restrict__ opb,
                                              float* __restrict__ pooled) {
    int b = blockIdx.x;
    int f = threadIdx.x;  // 128
    __shared__ float es[4][128], qs[4][128], ks[4][128], vs[4][128], sc[128], cx[4][128];
#pragma unroll
    for (int g = 0; g < 4; ++g) {
        float c = cnt[g * Bq + b];
        es[g][f] = (c > 0.f) ? emb_sum[(g * Bq + b) * Hn + f] / c : 0.f;
    }
    __syncthreads();
#pragma unroll
    for (int g = 0; g < 4; ++g) {
        float q = ipb[f], k = ipb[Hn + f], v = ipb[2 * Hn + f];
        for (int j = 0; j < Hn; ++j) {
            float e = es[g][j];
            q += e * ipw[f * Hn + j];
            k += e * ipw[(Hn + f) * Hn + j];
            v += e * ipw[(2 * Hn + f) * Hn + j];
        }
        qs[g][f] = q; ks[g][f] = k; vs[g][f] = v;
    }
    __syncthreads();
    {
        int h = f >> 4, g = (f >> 2) & 3, kk = f & 3;
        float s = 0.f;
        for (int d = 0; d < 16; ++d) s += qs[g][h * 16 + d] * ks[kk][h * 16 + d];
        sc[f] = s * 0.25f;
    }
    __syncthreads();
    {
        int h = f >> 4;
#pragma unroll
        for (int g = 0; g < 4; ++g) {
            int bi = h * 16 + g * 4;
            float s0 = sc[bi], s1 = sc[bi + 1], s2 = sc[bi + 2], s3 = sc[bi + 3];
            float m = fmaxf(fmaxf(s0, s1), fmaxf(s2, s3));
            float e0 = __expf(s0 - m), e1 = __expf(s1 - m), e2 = __expf(s2 - m), e3 = __expf(s3 - m);
            float rinv = 1.f / (e0 + e1 + e2 + e3);
            cx[g][f] = (e0 * vs[0][f] + e1 * vs[1][f] + e2 * vs[2][f] + e3 * vs[3][f]) * rinv;
        }
    }
    __syncthreads();
#pragma unroll
    for (int g = 0; g < 4; ++g) {
        float a = opb[f];
        for (int j = 0; j < Hn; ++j) a += cx[g][j] * opw[f * Hn + j];
        atomicAdd(&pooled[g * Hn + f], a * (1.0f / Bq));
    }
}

// ---------------- final: out[g,n] = (pooled[g] . lin_w[n] + lin_b[n]) * 60 + 50 ----------------
__global__ __launch_bounds__(256) void k_final(const float* __restrict__ pooled, const float* __restrict__ lw,
                                               const float* __restrict__ lb, float* __restrict__ out) {
    __shared__ float ps[512];
    int t = threadIdx.x;
    ps[t] = pooled[t];
    ps[t + 256] = pooled[t + 256];
    __syncthreads();
    int wave = t >> 6, lane = t & 63;
    int n = blockIdx.x * 4 + wave;
    if (n >= NNODES) return;
    float2 w = *(const float2*)&lw[(long)n * 128 + lane * 2];
    float a0 = w.x * ps[0 * 128 + lane * 2] + w.y * ps[0 * 128 + lane * 2 + 1];
    float a1 = w.x * ps[1 * 128 + lane * 2] + w.y * ps[1 * 128 + lane * 2 + 1];
    float a2 = w.x * ps[2 * 128 + lane * 2] + w.y * ps[2 * 128 + lane * 2 + 1];
    float a3 = w.x * ps[3 * 128 + lane * 2] + w.y * ps[3 * 128 + lane * 2 + 1];
#pragma unroll
    for (int off = 32; off > 0; off >>= 1) {
        a0 += __shfl_down(a0, off);
        a1 += __shfl_down(a1, off);
        a2 += __shfl_down(a2, off);
        a3 += __shfl_down(a3, off);
    }
    if (lane == 0) {
        float bn = lb[n];
        out[0 * NNODES + n] = (a0 + bn) * 60.f + 50.f;
        out[1 * NNODES + n] = (a1 + bn) * 60.f + 50.f;
        out[2 * NNODES + n] = (a2 + bn) * 60.f + 50.f;
        out[3 * NNODES + n] = (a3 + bn) * 60.f + 50.f;
    }
}

extern "C" void kernel_launch(void* const* d_in, const int* in_sizes, int n_in,
                              void* d_out, int out_size, void* d_ws, size_t ws_size,
                              hipStream_t stream) {
    const float* x   = (const float*)d_in[0];
    const int*   ei  = (const int*)d_in[1];
    const int*   bat = (const int*)d_in[2];
    const float* W1  = (const float*)d_in[3];
    const float* b1  = (const float*)d_in[4];
    const float* W2  = (const float*)d_in[5];
    const float* b2  = (const float*)d_in[6];
    const float* ipw = (const float*)d_in[7];
    const float* ipb = (const float*)d_in[8];
    const float* opw = (const float*)d_in[9];
    const float* opb = (const float*)d_in[10];
    const float* lw  = (const float*)d_in[11];
    const float* lb  = (const float*)d_in[12];
    float* out = (float*)d_out;

    // workspace carve-up.  y2f (fp32 [N,128], 25.6MB) ALIASES xb+z1 (both dead by mm2).
    char* p = (char*)d_ws;
    float*          y2f = (float*)p;                         // [N,128] fp32   25.6 MB
    unsigned short* xb  = (unsigned short*)p;                // [N,64]  bf16    6.4 MB (alias)
    unsigned short* z1  = xb + (size_t)Nn * 64;              // [N,64]  bf16    6.4 MB (alias)
    unsigned short* y1b = (unsigned short*)(p + 25600000);   // [N,128] bf16   12.8 MB
    unsigned short* z2  = (unsigned short*)(p + 38400000);   // [N,128] bf16   12.8 MB
    int*   degi   = (int*)(p + 51200000);                    // [N]
    int*   off    = degi + Nn;                               // [N+1]
    int*   cur    = off + Nn + 1;                            // [N]
    int*   srcs   = cur + Nn;                                // [E]
    float* wts    = (float*)(srcs + En);                     // [E]
    float* emb    = wts + En;                                // [G,B,H]
    float* cnt    = emb + Gn * Bq * Hn;                      // [G,B]
    float* pooled = cnt + Gn * Bq;                           // [G,H]

    hipMemsetAsync(emb, 0, Gn * Bq * Hn * sizeof(float), stream);
    hipMemsetAsync(cnt, 0, Gn * Bq * sizeof(float), stream);
    hipMemsetAsync(pooled, 0, Gn * Hn * sizeof(float), stream);

    const int mmGrid = (Nn + 31) / 32;       // 1563
    const int egGrid = (En + 255) / 256;     // 3125
    const int agGrid = (Nn + 7) / 8;         // 6250
    const int plGrid = (Nn + 255) / 256;     // 196
    const int ctGrid = (Nn * F_IN / 4 + 255) / 256;  // 3125

    for (int g = 0; g < Gn; ++g) {
        const int* row = ei + (size_t)g * 2 * En;
        const int* col = row + En;
        const float* xg = x + (size_t)g * Nn * F_IN;
        const int* bg = bat + (size_t)g * Nn;

        k_cast<<<ctGrid, 256, 0, stream>>>(xg, xb);

        hipMemsetAsync(degi, 0, Nn * sizeof(int), stream);
        k_deg<<<egGrid, 256, 0, stream>>>(col, degi);
        k_scan<<<1, 1024, 0, stream>>>(degi, off, cur);
        k_fill<<<egGrid, 256, 0, stream>>>(row, col, degi, off, cur, srcs, wts);

        // layer 1: z1 = agg(xb); y1b = relu(z1@W1 + b1)  (agg-before-project)
        k_agg1<<<agGrid, 256, 0, stream>>>(xb, off, srcs, wts, degi, z1);
        k_mm<64, 1><<<mmGrid, 256, 0, stream>>>(z1, W1, b1, (void*)y1b, Nn);

        // layer 2: z2 = agg(y1b); y2 = relu(z2@W2 + b2)
        k_agg2<<<agGrid, 256, 0, stream>>>(y1b, off, srcs, wts, degi, z2);
        k_mm<128, 0><<<mmGrid, 256, 0, stream>>>(z2, W2, b2, (void*)y2f, Nn);

        // pool
        k_pool<<<plGrid, 128, 0, stream>>>(y2f, bg, emb, cnt, g);
    }

    k_attn<<<Bq, 128, 0, stream>>>(emb, cnt, ipw, ipb, opw, opb, pooled);
    k_final<<<(NNODES + 3) / 4, 256, 0, stream>>>(pooled, lw, lb, out);
}

// Round 4
// 1155.839 us; speedup vs baseline: 11.1474x; 1.5249x over previous
//
#include <hip/hip_runtime.h>

#define Gn 4
#define Nn 50000
#define En 800000
#define Bq 32
#define F_IN 64
#define Hn 128
#define HEADS 8
#define HD 16
#define NNODES 50000
#define NB 196  // (Nn+255)/256

// ---- bf16 helpers (RNE) ----
__device__ __forceinline__ float bf2f(unsigned short u) {
    unsigned int x = ((unsigned int)u) << 16;
    float f; __builtin_memcpy(&f, &x, 4); return f;
}
__device__ __forceinline__ unsigned short f2bf(float f) {
    unsigned int x; __builtin_memcpy(&x, &f, 4);
    x = (x + 0x7fffu + ((x >> 16) & 1u)) >> 16;
    return (unsigned short)x;
}

// ---------------- cast fp32 x -> bf16 xb ----------------
__global__ __launch_bounds__(256) void k_cast(const float* __restrict__ x, unsigned short* __restrict__ xb) {
    int i = blockIdx.x * 256 + threadIdx.x;  // one float4 per thread
    if (i >= Nn * F_IN / 4) return;
    float4 v = *(const float4*)&x[i * 4];
    ushort4 u = make_ushort4(f2bf(v.x), f2bf(v.y), f2bf(v.z), f2bf(v.w));
    *(ushort4*)&xb[i * 4] = u;
}

// ---------------- degree ----------------
__global__ __launch_bounds__(256) void k_deg(const int* __restrict__ col, int* __restrict__ degi) {
    int e = blockIdx.x * 256 + threadIdx.x;
    if (e < En) atomicAdd(&degi[col[e]], 1);
}

// ---------------- parallel scan stage 1: per-block sums ----------------
__global__ __launch_bounds__(256) void k_bsum(const int* __restrict__ degi, int* __restrict__ bsum) {
    __shared__ int red[4];
    int i = blockIdx.x * 256 + threadIdx.x;
    int v = (i < Nn) ? degi[i] : 0;
#pragma unroll
    for (int off = 32; off > 0; off >>= 1) v += __shfl_down(v, off, 64);
    if ((threadIdx.x & 63) == 0) red[threadIdx.x >> 6] = v;
    __syncthreads();
    if (threadIdx.x == 0) bsum[blockIdx.x] = red[0] + red[1] + red[2] + red[3];
}

// ---------------- parallel scan stage 2: exclusive scan of NB block sums (1 tiny block) ----------------
__global__ __launch_bounds__(256) void k_bscan(int* __restrict__ bsum) {
    __shared__ int s[256];
    int t = threadIdx.x;
    int v = (t < NB) ? bsum[t] : 0;
    s[t] = v;
    __syncthreads();
    for (int d = 1; d < 256; d <<= 1) {
        int u = (t >= d) ? s[t - d] : 0;
        __syncthreads();
        s[t] += u;
        __syncthreads();
    }
    if (t < NB) bsum[t] = (t > 0) ? s[t - 1] : 0;  // exclusive base per block
}

// ---------------- parallel scan stage 3: per-block offsets + zero cursors ----------------
__global__ __launch_bounds__(256) void k_off(const int* __restrict__ degi, const int* __restrict__ bbase,
                                             int* __restrict__ off, int* __restrict__ cur) {
    __shared__ int s[256];
    int b = blockIdx.x, t = threadIdx.x;
    int i = b * 256 + t;
    int d = (i < Nn) ? degi[i] : 0;
    s[t] = d;
    __syncthreads();
    for (int dd = 1; dd < 256; dd <<= 1) {
        int u = (t >= dd) ? s[t - dd] : 0;
        __syncthreads();
        s[t] += u;
        __syncthreads();
    }
    if (i < Nn) {
        int base = bbase[b];
        off[i] = base + s[t] - d;  // exclusive
        cur[i] = 0;
        if (i == Nn - 1) off[Nn] = base + s[t];
    }
}

// ---------------- fill CSR (dest-sorted) ----------------
__global__ __launch_bounds__(256) void k_fill(const int* __restrict__ row, const int* __restrict__ col,
                                              const int* __restrict__ degi, const int* __restrict__ off,
                                              int* __restrict__ cur, int* __restrict__ srcs,
                                              float* __restrict__ wts) {
    int e = blockIdx.x * 256 + threadIdx.x;
    if (e >= En) return;
    int r = row[e], c = col[e];
    float w = rsqrtf((float)degi[r] + 1.0f) * rsqrtf((float)degi[c] + 1.0f);
    int pos = off[c] + atomicAdd(&cur[c], 1);
    srcs[pos] = r;
    wts[pos] = w;
}

// ---------------- agg on 64-feat bf16 (layer-1, pre-projection) ----------------
__global__ __launch_bounds__(256) void k_agg1(const unsigned short* __restrict__ xb, const int* __restrict__ off,
                                              const int* __restrict__ srcs, const float* __restrict__ wts,
                                              const int* __restrict__ degi, unsigned short* __restrict__ z1) {
    int node = blockIdx.x * 8 + (threadIdx.x >> 5);
    int lane = threadIdx.x & 31;
    int f2 = lane << 1;
    int beg = off[node], end = off[node + 1];
    float ax = 0.f, ay = 0.f;
    for (int e = beg; e < end; e += 32) {
        int k = min(32, end - e);
        int sid = 0; float w = 0.f;
        if (lane < k) { sid = srcs[e + lane]; w = wts[e + lane]; }
        for (int j = 0; j < k; ++j) {
            int s = __shfl(sid, j, 32);
            float ww = __shfl(w, j, 32);
            ushort2 u = *(const ushort2*)&xb[(long)s * 64 + f2];
            ax += bf2f(u.x) * ww;
            ay += bf2f(u.y) * ww;
        }
    }
    float inv = 1.0f / ((float)degi[node] + 1.0f);
    ushort2 su = *(const ushort2*)&xb[(long)node * 64 + f2];
    ax += bf2f(su.x) * inv;
    ay += bf2f(su.y) * inv;
    *(ushort2*)&z1[(long)node * 64 + f2] = make_ushort2(f2bf(ax), f2bf(ay));
}

// ---------------- agg on 128-feat bf16 (layer-2, pre-projection) ----------------
__global__ __launch_bounds__(256) void k_agg2(const unsigned short* __restrict__ h, const int* __restrict__ off,
                                              const int* __restrict__ srcs, const float* __restrict__ wts,
                                              const int* __restrict__ degi, unsigned short* __restrict__ z2) {
    int node = blockIdx.x * 8 + (threadIdx.x >> 5);
    int lane = threadIdx.x & 31;
    int f4 = lane << 2;
    int beg = off[node], end = off[node + 1];
    float a0 = 0.f, a1 = 0.f, a2 = 0.f, a3 = 0.f;
    for (int e = beg; e < end; e += 32) {
        int k = min(32, end - e);
        int sid = 0; float w = 0.f;
        if (lane < k) { sid = srcs[e + lane]; w = wts[e + lane]; }
        for (int j = 0; j < k; ++j) {
            int s = __shfl(sid, j, 32);
            float ww = __shfl(w, j, 32);
            ushort4 u = *(const ushort4*)&h[(long)s * 128 + f4];
            a0 += bf2f(u.x) * ww;
            a1 += bf2f(u.y) * ww;
            a2 += bf2f(u.z) * ww;
            a3 += bf2f(u.w) * ww;
        }
    }
    float inv = 1.0f / ((float)degi[node] + 1.0f);
    ushort4 su = *(const ushort4*)&h[(long)node * 128 + f4];
    a0 += bf2f(su.x) * inv;
    a1 += bf2f(su.y) * inv;
    a2 += bf2f(su.z) * inv;
    a3 += bf2f(su.w) * inv;
    *(ushort4*)&z2[(long)node * 128 + f4] = make_ushort4(f2bf(a0), f2bf(a1), f2bf(a2), f2bf(a3));
}

// ---------------- mm: out_bf16 = relu(zin_bf16[N,K] @ W[K,128] + b) ----------------
template <int K>
__global__ __launch_bounds__(256, 3) void k_mm(const unsigned short* __restrict__ zin,
                                               const float* __restrict__ W, const float* __restrict__ bias,
                                               unsigned short* __restrict__ outp, int nrows) {
    __shared__ float Ws[64 * 128];
    __shared__ float xsT[64 * 36];
    int t = threadIdx.x;
    int tx = t & 31, ty = t >> 5;
    int base = blockIdx.x * 32;
    float acc[4][4];
#pragma unroll
    for (int i = 0; i < 4; ++i)
#pragma unroll
        for (int j = 0; j < 4; ++j) acc[i][j] = 0.f;

    for (int kt = 0; kt < K; kt += 64) {
        const float4* W4 = (const float4*)(W + kt * 128);
        float4* Ws4 = (float4*)Ws;
#pragma unroll
        for (int i = 0; i < 8; ++i) Ws4[t + i * 256] = W4[t + i * 256];
        {
            int r = t >> 4, j4 = (t & 15) << 2;
#pragma unroll
            for (int p = 0; p < 2; ++p) {
                int rr = r + p * 16;
                int grow = base + rr;
                ushort4 u = make_ushort4(0, 0, 0, 0);
                if (grow < nrows) u = *(const ushort4*)&zin[(long)grow * K + kt + j4];
                xsT[(j4 + 0) * 36 + rr] = bf2f(u.x);
                xsT[(j4 + 1) * 36 + rr] = bf2f(u.y);
                xsT[(j4 + 2) * 36 + rr] = bf2f(u.z);
                xsT[(j4 + 3) * 36 + rr] = bf2f(u.w);
            }
        }
        __syncthreads();
#pragma unroll 8
        for (int jj = 0; jj < 64; ++jj) {
            float4 wv = *(const float4*)&Ws[jj * 128 + tx * 4];
            float4 xv = *(const float4*)&xsT[jj * 36 + ty * 4];
            acc[0][0] += xv.x * wv.x; acc[0][1] += xv.x * wv.y; acc[0][2] += xv.x * wv.z; acc[0][3] += xv.x * wv.w;
            acc[1][0] += xv.y * wv.x; acc[1][1] += xv.y * wv.y; acc[1][2] += xv.y * wv.z; acc[1][3] += xv.y * wv.w;
            acc[2][0] += xv.z * wv.x; acc[2][1] += xv.z * wv.y; acc[2][2] += xv.z * wv.z; acc[2][3] += xv.z * wv.w;
            acc[3][0] += xv.w * wv.x; acc[3][1] += xv.w * wv.y; acc[3][2] += xv.w * wv.z; acc[3][3] += xv.w * wv.w;
        }
        __syncthreads();
    }
    float4 bv = *(const float4*)&bias[tx * 4];
#pragma unroll
    for (int i = 0; i < 4; ++i) {
        int r = base + ty * 4 + i;
        if (r < nrows) {
            float o0 = fmaxf(acc[i][0] + bv.x, 0.f);
            float o1 = fmaxf(acc[i][1] + bv.y, 0.f);
            float o2 = fmaxf(acc[i][2] + bv.z, 0.f);
            float o3 = fmaxf(acc[i][3] + bv.w, 0.f);
            ushort4 st = make_ushort4(f2bf(o0), f2bf(o1), f2bf(o2), f2bf(o3));
            *(ushort4*)&outp[(long)r * 128 + tx * 4] = st;
        }
    }
}

// ---------------- segment mean pool (batch sorted), bf16 input ----------------
__global__ __launch_bounds__(128) void k_pool(const unsigned short* __restrict__ y, const int* __restrict__ batch,
                                              float* __restrict__ emb_sum, float* __restrict__ cnt, int g) {
    int f = threadIdx.x;  // 128
    int start = blockIdx.x * 64;
    int end = min(start + 64, Nn);
    if (start >= Nn) return;
    float acc = 0.f;
    int cacc = 0;
    int cur = batch[start];
    for (int i = start; i < end; ++i) {
        int b = batch[i];
        if (b != cur) {
            atomicAdd(&emb_sum[(g * Bq + cur) * Hn + f], acc);
            if (f == 0) atomicAdd(&cnt[g * Bq + cur], (float)cacc);
            acc = 0.f; cacc = 0; cur = b;
        }
        acc += bf2f(y[(long)i * Hn + f]);
        cacc++;
    }
    atomicAdd(&emb_sum[(g * Bq + cur) * Hn + f], acc);
    if (f == 0) atomicAdd(&cnt[g * Bq + cur], (float)cacc);
}

// ---------------- whole MHA: one block per batch element b ----------------
__global__ __launch_bounds__(128) void k_attn(const float* __restrict__ emb_sum, const float* __restrict__ cnt,
                                              const float* __restrict__ ipw, const float* __restrict__ ipb,
                                              const float* __restrict__ opw, const float* __restrict__ opb,
                                              float* __restrict__ pooled) {
    int b = blockIdx.x;
    int f = threadIdx.x;  // 128
    __shared__ float es[4][128], qs[4][128], ks[4][128], vs[4][128], sc[128], cx[4][128];
#pragma unroll
    for (int g = 0; g < 4; ++g) {
        float c = cnt[g * Bq + b];
        es[g][f] = (c > 0.f) ? emb_sum[(g * Bq + b) * Hn + f] / c : 0.f;
    }
    __syncthreads();
#pragma unroll
    for (int g = 0; g < 4; ++g) {
        float q = ipb[f], k = ipb[Hn + f], v = ipb[2 * Hn + f];
        for (int j = 0; j < Hn; ++j) {
            float e = es[g][j];
            q += e * ipw[f * Hn + j];
            k += e * ipw[(Hn + f) * Hn + j];
            v += e * ipw[(2 * Hn + f) * Hn + j];
        }
        qs[g][f] = q; ks[g][f] = k; vs[g][f] = v;
    }
    __syncthreads();
    {
        int h = f >> 4, g = (f >> 2) & 3, kk = f & 3;
        float s = 0.f;
        for (int d = 0; d < 16; ++d) s += qs[g][h * 16 + d] * ks[kk][h * 16 + d];
        sc[f] = s * 0.25f;
    }
    __syncthreads();
    {
        int h = f >> 4;
#pragma unroll
        for (int g = 0; g < 4; ++g) {
            int bi = h * 16 + g * 4;
            float s0 = sc[bi], s1 = sc[bi + 1], s2 = sc[bi + 2], s3 = sc[bi + 3];
            float m = fmaxf(fmaxf(s0, s1), fmaxf(s2, s3));
            float e0 = __expf(s0 - m), e1 = __expf(s1 - m), e2 = __expf(s2 - m), e3 = __expf(s3 - m);
            float rinv = 1.f / (e0 + e1 + e2 + e3);
            cx[g][f] = (e0 * vs[0][f] + e1 * vs[1][f] + e2 * vs[2][f] + e3 * vs[3][f]) * rinv;
        }
    }
    __syncthreads();
#pragma unroll
    for (int g = 0; g < 4; ++g) {
        float a = opb[f];
        for (int j = 0; j < Hn; ++j) a += cx[g][j] * opw[f * Hn + j];
        atomicAdd(&pooled[g * Hn + f], a * (1.0f / Bq));
    }
}

// ---------------- final: out[g,n] = (pooled[g] . lin_w[n] + lin_b[n]) * 60 + 50 ----------------
__global__ __launch_bounds__(256) void k_final(const float* __restrict__ pooled, const float* __restrict__ lw,
                                               const float* __restrict__ lb, float* __restrict__ out) {
    __shared__ float ps[512];
    int t = threadIdx.x;
    ps[t] = pooled[t];
    ps[t + 256] = pooled[t + 256];
    __syncthreads();
    int wave = t >> 6, lane = t & 63;
    int n = blockIdx.x * 4 + wave;
    if (n >= NNODES) return;
    float2 w = *(const float2*)&lw[(long)n * 128 + lane * 2];
    float a0 = w.x * ps[0 * 128 + lane * 2] + w.y * ps[0 * 128 + lane * 2 + 1];
    float a1 = w.x * ps[1 * 128 + lane * 2] + w.y * ps[1 * 128 + lane * 2 + 1];
    float a2 = w.x * ps[2 * 128 + lane * 2] + w.y * ps[2 * 128 + lane * 2 + 1];
    float a3 = w.x * ps[3 * 128 + lane * 2] + w.y * ps[3 * 128 + lane * 2 + 1];
#pragma unroll
    for (int off = 32; off > 0; off >>= 1) {
        a0 += __shfl_down(a0, off);
        a1 += __shfl_down(a1, off);
        a2 += __shfl_down(a2, off);
        a3 += __shfl_down(a3, off);
    }
    if (lane == 0) {
        float bn = lb[n];
        out[0 * NNODES + n] = (a0 + bn) * 60.f + 50.f;
        out[1 * NNODES + n] = (a1 + bn) * 60.f + 50.f;
        out[2 * NNODES + n] = (a2 + bn) * 60.f + 50.f;
        out[3 * NNODES + n] = (a3 + bn) * 60.f + 50.f;
    }
}

extern "C" void kernel_launch(void* const* d_in, const int* in_sizes, int n_in,
                              void* d_out, int out_size, void* d_ws, size_t ws_size,
                              hipStream_t stream) {
    const float* x   = (const float*)d_in[0];
    const int*   ei  = (const int*)d_in[1];
    const int*   bat = (const int*)d_in[2];
    const float* W1  = (const float*)d_in[3];
    const float* b1  = (const float*)d_in[4];
    const float* W2  = (const float*)d_in[5];
    const float* b2  = (const float*)d_in[6];
    const float* ipw = (const float*)d_in[7];
    const float* ipb = (const float*)d_in[8];
    const float* opw = (const float*)d_in[9];
    const float* opb = (const float*)d_in[10];
    const float* lw  = (const float*)d_in[11];
    const float* lb  = (const float*)d_in[12];
    float* out = (float*)d_out;

    // workspace carve-up
    char* p = (char*)d_ws;
    unsigned short* xb  = (unsigned short*)p;                // [N,64]  bf16    6.4 MB
    unsigned short* z1  = xb + (size_t)Nn * 64;              // [N,64]  bf16    6.4 MB
    unsigned short* y1b = (unsigned short*)(p + 12800000);   // [N,128] bf16   12.8 MB
    unsigned short* z2  = (unsigned short*)(p + 25600000);   // [N,128] bf16   12.8 MB
    unsigned short* y2b = (unsigned short*)(p + 38400000);   // [N,128] bf16   12.8 MB
    int*   degi   = (int*)(p + 51200000);                    // [N]
    int*   off    = degi + Nn;                               // [N+1]
    int*   cur    = off + Nn + 1;                            // [N]
    int*   bsum   = cur + Nn;                                // [NB]
    int*   srcs   = bsum + 256;                              // [E]
    float* wts    = (float*)(srcs + En);                     // [E]
    float* emb    = wts + En;                                // [G,B,H]
    float* cnt    = emb + Gn * Bq * Hn;                      // [G,B]
    float* pooled = cnt + Gn * Bq;                           // [G,H]

    hipMemsetAsync(emb, 0, Gn * Bq * Hn * sizeof(float), stream);
    hipMemsetAsync(cnt, 0, Gn * Bq * sizeof(float), stream);
    hipMemsetAsync(pooled, 0, Gn * Hn * sizeof(float), stream);

    const int mmGrid = (Nn + 31) / 32;       // 1563
    const int egGrid = (En + 255) / 256;     // 3125
    const int agGrid = (Nn + 7) / 8;         // 6250
    const int plGrid = (Nn + 63) / 64;       // 782
    const int ctGrid = (Nn * F_IN / 4 + 255) / 256;  // 3125

    for (int g = 0; g < Gn; ++g) {
        const int* row = ei + (size_t)g * 2 * En;
        const int* col = row + En;
        const float* xg = x + (size_t)g * Nn * F_IN;
        const int* bg = bat + (size_t)g * Nn;

        k_cast<<<ctGrid, 256, 0, stream>>>(xg, xb);

        // CSR build with parallel 3-stage scan
        hipMemsetAsync(degi, 0, Nn * sizeof(int), stream);
        k_deg<<<egGrid, 256, 0, stream>>>(col, degi);
        k_bsum<<<NB, 256, 0, stream>>>(degi, bsum);
        k_bscan<<<1, 256, 0, stream>>>(bsum);
        k_off<<<NB, 256, 0, stream>>>(degi, bsum, off, cur);
        k_fill<<<egGrid, 256, 0, stream>>>(row, col, degi, off, cur, srcs, wts);

        // layer 1: z1 = agg(xb); y1b = relu(z1@W1 + b1)  (agg-before-project)
        k_agg1<<<agGrid, 256, 0, stream>>>(xb, off, srcs, wts, degi, z1);
        k_mm<64><<<mmGrid, 256, 0, stream>>>(z1, W1, b1, y1b, Nn);

        // layer 2: z2 = agg(y1b); y2b = relu(z2@W2 + b2)
        k_agg2<<<agGrid, 256, 0, stream>>>(y1b, off, srcs, wts, degi, z2);
        k_mm<128><<<mmGrid, 256, 0, stream>>>(z2, W2, b2, y2b, Nn);

        // pool
        k_pool<<<plGrid, 128, 0, stream>>>(y2b, bg, emb, cnt, g);
    }

    k_attn<<<Bq, 128, 0, stream>>>(emb, cnt, ipw, ipb, opw, opb, pooled);
    k_final<<<(NNODES + 3) / 4, 256, 0, stream>>>(pooled, lw, lb, out);
}

// Round 5
// 978.904 us; speedup vs baseline: 13.1622x; 1.1807x over previous
//
#include <hip/hip_runtime.h>

#define Gn 4
#define Nn 50000
#define En 800000
#define Bq 32
#define F_IN 64
#define Hn 128
#define HEADS 8
#define HD 16
#define NNODES 50000
#define NB 196  // (Nn+255)/256

using v8s = __attribute__((ext_vector_type(8))) short;
using v4f = __attribute__((ext_vector_type(4))) float;

// ---- bf16 helpers (RNE) ----
__device__ __forceinline__ float bf2f(unsigned short u) {
    unsigned int x = ((unsigned int)u) << 16;
    float f; __builtin_memcpy(&f, &x, 4); return f;
}
__device__ __forceinline__ unsigned short f2bf(float f) {
    unsigned int x; __builtin_memcpy(&x, &f, 4);
    x = (x + 0x7fffu + ((x >> 16) & 1u)) >> 16;
    return (unsigned short)x;
}

// ---------------- degree over all 4 graphs (grid.y = g) ----------------
__global__ __launch_bounds__(256) void k_deg4(const int* __restrict__ ei, int* __restrict__ degi) {
    int g = blockIdx.y;
    int e = blockIdx.x * 256 + threadIdx.x;
    if (e >= En) return;
    const int* col = ei + (size_t)g * 2 * En + En;
    atomicAdd(&degi[g * Nn + col[e]], 1);
}

// ---------------- scan stage 1: per-block sums ----------------
__global__ __launch_bounds__(256) void k_bsum4(const int* __restrict__ degi, int* __restrict__ bsum) {
    __shared__ int red[4];
    int g = blockIdx.y;
    int i = blockIdx.x * 256 + threadIdx.x;
    int v = (i < Nn) ? degi[g * Nn + i] : 0;
#pragma unroll
    for (int off = 32; off > 0; off >>= 1) v += __shfl_down(v, off, 64);
    if ((threadIdx.x & 63) == 0) red[threadIdx.x >> 6] = v;
    __syncthreads();
    if (threadIdx.x == 0) bsum[g * 256 + blockIdx.x] = red[0] + red[1] + red[2] + red[3];
}

// ---------------- scan stage 2: exclusive scan of NB block sums per graph ----------------
__global__ __launch_bounds__(256) void k_bscan4(int* __restrict__ bsum) {
    __shared__ int s[256];
    int g = blockIdx.x, t = threadIdx.x;
    int v = (t < NB) ? bsum[g * 256 + t] : 0;
    s[t] = v;
    __syncthreads();
    for (int d = 1; d < 256; d <<= 1) {
        int u = (t >= d) ? s[t - d] : 0;
        __syncthreads();
        s[t] += u;
        __syncthreads();
    }
    if (t < NB) bsum[g * 256 + t] = (t > 0) ? s[t - 1] : 0;
}

// ---------------- scan stage 3: offsets + cursors + dinv ----------------
__global__ __launch_bounds__(256) void k_off4(const int* __restrict__ degi, const int* __restrict__ bbase,
                                              int* __restrict__ off, int* __restrict__ cur,
                                              float* __restrict__ dinv) {
    __shared__ int s[256];
    int g = blockIdx.y, b = blockIdx.x, t = threadIdx.x;
    int i = b * 256 + t;
    int d = (i < Nn) ? degi[g * Nn + i] : 0;
    s[t] = d;
    __syncthreads();
    for (int dd = 1; dd < 256; dd <<= 1) {
        int u = (t >= dd) ? s[t - dd] : 0;
        __syncthreads();
        s[t] += u;
        __syncthreads();
    }
    if (i < Nn) {
        int base = bbase[g * 256 + b];
        off[g * (Nn + 1) + i] = base + s[t] - d;
        cur[g * Nn + i] = 0;
        dinv[g * Nn + i] = rsqrtf((float)d + 1.0f);
        if (i == Nn - 1) off[g * (Nn + 1) + Nn] = base + s[t];
    }
}

// ---------------- fill CSR srcs (ushort, dest-sorted), all graphs ----------------
__global__ __launch_bounds__(256) void k_fill4(const int* __restrict__ ei, const int* __restrict__ off,
                                               int* __restrict__ cur, unsigned short* __restrict__ srcs) {
    int g = blockIdx.y;
    int e = blockIdx.x * 256 + threadIdx.x;
    if (e >= En) return;
    const int* row = ei + (size_t)g * 2 * En;
    const int* col = row + En;
    int r = row[e], c = col[e];
    int pos = off[g * (Nn + 1) + c] + atomicAdd(&cur[g * Nn + c], 1);
    srcs[(size_t)g * En + pos] = (unsigned short)r;
}

// ---------------- cast + pre-scale: xbs = bf16(x * dinv) ----------------
__global__ __launch_bounds__(256) void k_cast(const float* __restrict__ x, const float* __restrict__ dinv,
                                              unsigned short* __restrict__ xbs) {
    int i = blockIdx.x * 256 + threadIdx.x;  // one float4 per thread, N*16 total
    if (i >= Nn * 16) return;
    float dc = dinv[i >> 4];
    float4 v = *(const float4*)&x[i * 4];
    ushort4 u = make_ushort4(f2bf(v.x * dc), f2bf(v.y * dc), f2bf(v.z * dc), f2bf(v.w * dc));
    *(ushort4*)&xbs[i * 4] = u;
}

// ---------------- agg 64-feat: z1 = dinv_c * (sum_e xs_r + xs_c) ----------------
__global__ __launch_bounds__(256) void k_agg1(const unsigned short* __restrict__ xs, const int* __restrict__ off,
                                              const unsigned short* __restrict__ srcs,
                                              const float* __restrict__ dinv, unsigned short* __restrict__ z1) {
    int node = blockIdx.x * 8 + (threadIdx.x >> 5);
    int lane = threadIdx.x & 31;
    int f2 = lane << 1;
    int beg = off[node], end = off[node + 1];
    ushort2 own = *(const ushort2*)&xs[(long)node * 64 + f2];
    float ax = bf2f(own.x), ay = bf2f(own.y);
    for (int e = beg; e < end; e += 32) {
        int k = min(32, end - e);
        int sid = 0;
        if (lane < k) sid = srcs[e + lane];
        for (int j = 0; j < k; ++j) {
            int s = __shfl(sid, j, 32);
            ushort2 u = *(const ushort2*)&xs[(long)s * 64 + f2];
            ax += bf2f(u.x);
            ay += bf2f(u.y);
        }
    }
    float dc = dinv[node];
    *(ushort2*)&z1[(long)node * 64 + f2] = make_ushort2(f2bf(ax * dc), f2bf(ay * dc));
}

// ---------------- agg 128-feat: z2 = dinv_c * (sum_e y1s_r + y1s_c) ----------------
__global__ __launch_bounds__(256) void k_agg2(const unsigned short* __restrict__ h, const int* __restrict__ off,
                                              const unsigned short* __restrict__ srcs,
                                              const float* __restrict__ dinv, unsigned short* __restrict__ z2) {
    int node = blockIdx.x * 8 + (threadIdx.x >> 5);
    int lane = threadIdx.x & 31;
    int f4 = lane << 2;
    int beg = off[node], end = off[node + 1];
    ushort4 own = *(const ushort4*)&h[(long)node * 128 + f4];
    float a0 = bf2f(own.x), a1 = bf2f(own.y), a2 = bf2f(own.z), a3 = bf2f(own.w);
    for (int e = beg; e < end; e += 32) {
        int k = min(32, end - e);
        int sid = 0;
        if (lane < k) sid = srcs[e + lane];
        for (int j = 0; j < k; ++j) {
            int s = __shfl(sid, j, 32);
            ushort4 u = *(const ushort4*)&h[(long)s * 128 + f4];
            a0 += bf2f(u.x);
            a1 += bf2f(u.y);
            a2 += bf2f(u.z);
            a3 += bf2f(u.w);
        }
    }
    float dc = dinv[node];
    *(ushort4*)&z2[(long)node * 128 + f4] =
        make_ushort4(f2bf(a0 * dc), f2bf(a1 * dc), f2bf(a2 * dc), f2bf(a3 * dc));
}

// ---------------- MFMA mm: out_bf16 = relu(zin[N,K]bf16 @ W[K,128]f32 + b) [* dinv if SCALE] ----------------
// 32 rows/block, 256 thr = 4 waves: wm = w&1 (row half), wn = w>>1 (col half of 64).
template <int K, bool SCALE>
__global__ __launch_bounds__(256) void k_mmfma(const unsigned short* __restrict__ zin,
                                               const float* __restrict__ W, const float* __restrict__ bias,
                                               const float* __restrict__ dinv,
                                               unsigned short* __restrict__ outp, int nrows) {
    __shared__ __align__(16) unsigned short Wt[128 * (K + 8)];  // W transposed [n][k], bf16, +8 pad
    __shared__ __align__(16) unsigned short At[32 * (K + 8)];   // A rows [r][k], bf16
    int t = threadIdx.x;
    int base = blockIdx.x * 32;

    // stage W (global coalesced fp32 -> LDS transposed bf16)
#pragma unroll
    for (int i = 0; i < K * 128 / 256; ++i) {
        int idx = i * 256 + t;
        int k = idx >> 7, n = idx & 127;
        Wt[n * (K + 8) + k] = f2bf(W[idx]);
    }
    // stage A: 8 threads/row, K/8 cols each
    {
        int r = t >> 3, cb = (t & 7) * (K / 8);
        long grow = base + r;
#pragma unroll
        for (int j = 0; j < K / 32; ++j) {
            ushort4 u = make_ushort4(0, 0, 0, 0);
            if (grow < nrows) u = *(const ushort4*)&zin[grow * K + cb + j * 4];
            *(ushort4*)&At[r * (K + 8) + cb + j * 4] = u;
        }
    }
    __syncthreads();

    int w = t >> 6, lane = t & 63;
    int wm = w & 1, wn = w >> 1;
    int m = lane & 15, q = lane >> 4;
    v4f acc[4] = {};
    const unsigned short* Ap = &At[(wm * 16 + m) * (K + 8) + q * 8];
    const unsigned short* Bp = &Wt[(wn * 64 + m) * (K + 8) + q * 8];
    const int rstep = 16 * (K + 8);
#pragma unroll
    for (int ks = 0; ks < K / 32; ++ks) {
        v8s a = *(const v8s*)(Ap + ks * 32);
        v8s b0 = *(const v8s*)(Bp + 0 * rstep + ks * 32);
        v8s b1 = *(const v8s*)(Bp + 1 * rstep + ks * 32);
        v8s b2 = *(const v8s*)(Bp + 2 * rstep + ks * 32);
        v8s b3 = *(const v8s*)(Bp + 3 * rstep + ks * 32);
        acc[0] = __builtin_amdgcn_mfma_f32_16x16x32_bf16(a, b0, acc[0], 0, 0, 0);
        acc[1] = __builtin_amdgcn_mfma_f32_16x16x32_bf16(a, b1, acc[1], 0, 0, 0);
        acc[2] = __builtin_amdgcn_mfma_f32_16x16x32_bf16(a, b2, acc[2], 0, 0, 0);
        acc[3] = __builtin_amdgcn_mfma_f32_16x16x32_bf16(a, b3, acc[3], 0, 0, 0);
    }

    // epilogue: C row = q*4+reg, col = wn*64 + nt*16 + m
    int col0 = wn * 64 + m;
    int rbase = base + wm * 16 + q * 4;
    float dv[4];
#pragma unroll
    for (int rg = 0; rg < 4; ++rg)
        dv[rg] = SCALE ? ((rbase + rg < nrows) ? dinv[rbase + rg] : 1.f) : 1.f;
#pragma unroll
    for (int nt = 0; nt < 4; ++nt) {
        float bc = bias[col0 + nt * 16];
#pragma unroll
        for (int rg = 0; rg < 4; ++rg) {
            int row = rbase + rg;
            if (row < nrows) {
                float o = fmaxf(acc[nt][rg] + bc, 0.f);
                outp[(long)row * 128 + col0 + nt * 16] = f2bf(o * dv[rg]);
            }
        }
    }
}

// ---------------- segment mean pool (batch sorted), bf16 input ----------------
__global__ __launch_bounds__(128) void k_pool(const unsigned short* __restrict__ y, const int* __restrict__ batch,
                                              float* __restrict__ emb_sum, float* __restrict__ cnt, int g) {
    int f = threadIdx.x;  // 128
    int start = blockIdx.x * 64;
    int end = min(start + 64, Nn);
    if (start >= Nn) return;
    float acc = 0.f;
    int cacc = 0;
    int cur = batch[start];
    for (int i = start; i < end; ++i) {
        int b = batch[i];
        if (b != cur) {
            atomicAdd(&emb_sum[(g * Bq + cur) * Hn + f], acc);
            if (f == 0) atomicAdd(&cnt[g * Bq + cur], (float)cacc);
            acc = 0.f; cacc = 0; cur = b;
        }
        acc += bf2f(y[(long)i * Hn + f]);
        cacc++;
    }
    atomicAdd(&emb_sum[(g * Bq + cur) * Hn + f], acc);
    if (f == 0) atomicAdd(&cnt[g * Bq + cur], (float)cacc);
}

// ---------------- whole MHA: one block per batch element b ----------------
__global__ __launch_bounds__(128) void k_attn(const float* __restrict__ emb_sum, const float* __restrict__ cnt,
                                              const float* __restrict__ ipw, const float* __restrict__ ipb,
                                              const float* __restrict__ opw, const float* __restrict__ opb,
                                              float* __restrict__ pooled) {
    int b = blockIdx.x;
    int f = threadIdx.x;  // 128
    __shared__ float es[4][128], qs[4][128], ks[4][128], vs[4][128], sc[128], cx[4][128];
#pragma unroll
    for (int g = 0; g < 4; ++g) {
        float c = cnt[g * Bq + b];
        es[g][f] = (c > 0.f) ? emb_sum[(g * Bq + b) * Hn + f] / c : 0.f;
    }
    __syncthreads();
#pragma unroll
    for (int g = 0; g < 4; ++g) {
        float q = ipb[f], k = ipb[Hn + f], v = ipb[2 * Hn + f];
        for (int j = 0; j < Hn; ++j) {
            float e = es[g][j];
            q += e * ipw[f * Hn + j];
            k += e * ipw[(Hn + f) * Hn + j];
            v += e * ipw[(2 * Hn + f) * Hn + j];
        }
        qs[g][f] = q; ks[g][f] = k; vs[g][f] = v;
    }
    __syncthreads();
    {
        int h = f >> 4, g = (f >> 2) & 3, kk = f & 3;
        float s = 0.f;
        for (int d = 0; d < 16; ++d) s += qs[g][h * 16 + d] * ks[kk][h * 16 + d];
        sc[f] = s * 0.25f;
    }
    __syncthreads();
    {
        int h = f >> 4;
#pragma unroll
        for (int g = 0; g < 4; ++g) {
            int bi = h * 16 + g * 4;
            float s0 = sc[bi], s1 = sc[bi + 1], s2 = sc[bi + 2], s3 = sc[bi + 3];
            float m = fmaxf(fmaxf(s0, s1), fmaxf(s2, s3));
            float e0 = __expf(s0 - m), e1 = __expf(s1 - m), e2 = __expf(s2 - m), e3 = __expf(s3 - m);
            float rinv = 1.f / (e0 + e1 + e2 + e3);
            cx[g][f] = (e0 * vs[0][f] + e1 * vs[1][f] + e2 * vs[2][f] + e3 * vs[3][f]) * rinv;
        }
    }
    __syncthreads();
#pragma unroll
    for (int g = 0; g < 4; ++g) {
        float a = opb[f];
        for (int j = 0; j < Hn; ++j) a += cx[g][j] * opw[f * Hn + j];
        atomicAdd(&pooled[g * Hn + f], a * (1.0f / Bq));
    }
}

// ---------------- final: out[g,n] = (pooled[g] . lin_w[n] + lin_b[n]) * 60 + 50 ----------------
__global__ __launch_bounds__(256) void k_final(const float* __restrict__ pooled, const float* __restrict__ lw,
                                               const float* __restrict__ lb, float* __restrict__ out) {
    __shared__ float ps[512];
    int t = threadIdx.x;
    ps[t] = pooled[t];
    ps[t + 256] = pooled[t + 256];
    __syncthreads();
    int wave = t >> 6, lane = t & 63;
    int n = blockIdx.x * 4 + wave;
    if (n >= NNODES) return;
    float2 w = *(const float2*)&lw[(long)n * 128 + lane * 2];
    float a0 = w.x * ps[0 * 128 + lane * 2] + w.y * ps[0 * 128 + lane * 2 + 1];
    float a1 = w.x * ps[1 * 128 + lane * 2] + w.y * ps[1 * 128 + lane * 2 + 1];
    float a2 = w.x * ps[2 * 128 + lane * 2] + w.y * ps[2 * 128 + lane * 2 + 1];
    float a3 = w.x * ps[3 * 128 + lane * 2] + w.y * ps[3 * 128 + lane * 2 + 1];
#pragma unroll
    for (int off = 32; off > 0; off >>= 1) {
        a0 += __shfl_down(a0, off);
        a1 += __shfl_down(a1, off);
        a2 += __shfl_down(a2, off);
        a3 += __shfl_down(a3, off);
    }
    if (lane == 0) {
        float bn = lb[n];
        out[0 * NNODES + n] = (a0 + bn) * 60.f + 50.f;
        out[1 * NNODES + n] = (a1 + bn) * 60.f + 50.f;
        out[2 * NNODES + n] = (a2 + bn) * 60.f + 50.f;
        out[3 * NNODES + n] = (a3 + bn) * 60.f + 50.f;
    }
}

extern "C" void kernel_launch(void* const* d_in, const int* in_sizes, int n_in,
                              void* d_out, int out_size, void* d_ws, size_t ws_size,
                              hipStream_t stream) {
    const float* x   = (const float*)d_in[0];
    const int*   ei  = (const int*)d_in[1];
    const int*   bat = (const int*)d_in[2];
    const float* W1  = (const float*)d_in[3];
    const float* b1  = (const float*)d_in[4];
    const float* W2  = (const float*)d_in[5];
    const float* b2  = (const float*)d_in[6];
    const float* ipw = (const float*)d_in[7];
    const float* ipb = (const float*)d_in[8];
    const float* opw = (const float*)d_in[9];
    const float* opb = (const float*)d_in[10];
    const float* lw  = (const float*)d_in[11];
    const float* lb  = (const float*)d_in[12];
    float* out = (float*)d_out;

    // workspace carve-up (~61 MB)
    char* p = (char*)d_ws;
    unsigned short* xbs = (unsigned short*)p;                // [N,64]  bf16    6.4 MB (per-graph reuse)
    unsigned short* z1  = xbs + (size_t)Nn * 64;             // [N,64]  bf16    6.4 MB
    unsigned short* y1b = (unsigned short*)(p + 12800000);   // [N,128] bf16   12.8 MB
    unsigned short* z2  = (unsigned short*)(p + 25600000);   // [N,128] bf16   12.8 MB
    unsigned short* y2b = (unsigned short*)(p + 38400000);   // [N,128] bf16   12.8 MB
    int*   degi = (int*)(p + 51200000);                      // [4][N]   0.8 MB
    int*   off  = degi + 4 * Nn;                             // [4][N+1] 0.8 MB
    int*   cur  = off + 4 * (Nn + 1);                        // [4][N]   0.8 MB
    float* dinv = (float*)(cur + 4 * Nn);                    // [4][N]   0.8 MB
    int*   bsum = (int*)(dinv + 4 * Nn);                     // [4][256]
    unsigned short* srcs = (unsigned short*)(bsum + 4 * 256);// [4][E] ushort 6.4 MB
    float* emb    = (float*)(srcs + (size_t)4 * En);         // [G,B,H]
    float* cnt    = emb + Gn * Bq * Hn;                      // [G,B]
    float* pooled = cnt + Gn * Bq;                           // [G,H]

    hipMemsetAsync(degi, 0, 4 * Nn * sizeof(int), stream);
    hipMemsetAsync(emb, 0, Gn * Bq * Hn * sizeof(float), stream);
    hipMemsetAsync(cnt, 0, Gn * Bq * sizeof(float), stream);
    hipMemsetAsync(pooled, 0, Gn * Hn * sizeof(float), stream);

    const int egGrid = (En + 255) / 256;             // 3125
    const int agGrid = (Nn + 7) / 8;                 // 6250
    const int mmGrid = (Nn + 31) / 32;               // 1563
    const int plGrid = (Nn + 63) / 64;               // 782
    const int ctGrid = (Nn * 16 + 255) / 256;        // 3125

    // CSR prep for all 4 graphs (merged launches)
    k_deg4<<<dim3(egGrid, 4), 256, 0, stream>>>(ei, degi);
    k_bsum4<<<dim3(NB, 4), 256, 0, stream>>>(degi, bsum);
    k_bscan4<<<4, 256, 0, stream>>>(bsum);
    k_off4<<<dim3(NB, 4), 256, 0, stream>>>(degi, bsum, off, cur, dinv);
    k_fill4<<<dim3(egGrid, 4), 256, 0, stream>>>(ei, off, cur, srcs);

    for (int g = 0; g < Gn; ++g) {
        const float* xg = x + (size_t)g * Nn * F_IN;
        const int* bg = bat + (size_t)g * Nn;
        const int* offg = off + g * (Nn + 1);
        const float* dinvg = dinv + g * Nn;
        const unsigned short* srcg = srcs + (size_t)g * En;

        k_cast<<<ctGrid, 256, 0, stream>>>(xg, dinvg, xbs);

        // layer 1: z1 = dinv*(sum xs + xs_self); y1s = relu(z1@W1+b1)*dinv
        k_agg1<<<agGrid, 256, 0, stream>>>(xbs, offg, srcg, dinvg, z1);
        k_mmfma<64, true><<<mmGrid, 256, 0, stream>>>(z1, W1, b1, dinvg, y1b, Nn);

        // layer 2: z2 = dinv*(sum y1s + y1s_self); y2 = relu(z2@W2+b2)
        k_agg2<<<agGrid, 256, 0, stream>>>(y1b, offg, srcg, dinvg, z2);
        k_mmfma<128, false><<<mmGrid, 256, 0, stream>>>(z2, W2, b2, dinvg, y2b, Nn);

        // pool
        k_pool<<<plGrid, 128, 0, stream>>>(y2b, bg, emb, cnt, g);
    }

    k_attn<<<Bq, 128, 0, stream>>>(emb, cnt, ipw, ipb, opw, opb, pooled);
    k_final<<<(NNODES + 3) / 4, 256, 0, stream>>>(pooled, lw, lb, out);
}